// Round 1
// baseline (1362.660 us; speedup 1.0000x reference)
//
#include <hip/hip_runtime.h>
#include <cstdint>

// Problem constants
#define T_ 64
#define A_ 48
#define NP_ 3072      // T*A pairs
#define E_ 22
#define RAW_ 512
#define H_ 256
#define NACT_ 21
#define NTP_ 3
#define PV_ 3456      // padded virtual pair rows (27 tiles of 128)
#define RV_ 68096     // padded virtual entity rows (532 tiles of 128)
#define NDEAD_ 67584  // NP_*E_

// ---------------------------------------------------------------------------
// K_bucket: sniff dead dtype, count pairs per type, build bucketed pair list.
// wsI layout: [0]=mode, [1..3]=cnt, [4..6]=ps, [8..10]=rs,
//             [16..16+PV)=pairIdx, then prb[PV]
// ---------------------------------------------------------------------------
__global__ void k_bucket(const unsigned* __restrict__ deadRaw,
                         const int* __restrict__ hete, int* __restrict__ wsI)
{
    __shared__ int fl[2];
    __shared__ int sc[3], cur[3], sps[3], srs[3];
    int tid = threadIdx.x;
    if (tid < 2) fl[tid] = 0;
    if (tid < 3) { sc[tid] = 0; cur[tid] = 0; }
    __syncthreads();
    // dtype sniff on first 4KB (safe: dead buffer >= 67584 bytes)
    int ni = 0, nf = 0;
    for (int i = tid; i < 1024; i += 256) {
        unsigned w = deadRaw[i];
        if (w > 1u) ni = 1;
        if (w != 0u && w != 0x3F800000u) nf = 1;
    }
    if (ni) atomicOr(&fl[0], 1);
    if (nf) atomicOr(&fl[1], 1);
    for (int p = tid; p < NP_; p += 256) atomicAdd(&sc[hete[p]], 1);
    __syncthreads();
    if (tid == 0) {
        int c0 = sc[0], c1 = sc[1], c2 = sc[2];
        int p1 = (c0 + 127) & ~127;
        int p2 = p1 + ((c1 + 127) & ~127);
        sps[0] = 0; sps[1] = p1; sps[2] = p2;
        int r1 = (22 * c0 + 127) & ~127;
        int r2 = r1 + ((22 * c1 + 127) & ~127);
        srs[0] = 0; srs[1] = r1; srs[2] = r2;
        // mode: 0=int32, 1=float32, 2=byte
        wsI[0] = fl[0] ? (fl[1] ? 2 : 1) : 0;
        wsI[1] = c0; wsI[2] = c1; wsI[3] = c2;
        wsI[4] = 0; wsI[5] = p1; wsI[6] = p2;
        wsI[8] = 0; wsI[9] = r1; wsI[10] = r2;
    }
    __syncthreads();
    int* pairIdx = wsI + 16;
    int* prb = pairIdx + PV_;
    for (int pv = tid; pv < PV_; pv += 256) pairIdx[pv] = -1;
    __syncthreads();
    for (int p = tid; p < NP_; p += 256) {
        int t = hete[p];
        int pos = atomicAdd(&cur[t], 1);
        pairIdx[sps[t] + pos] = p;
    }
    for (int pv = tid; pv < PV_; pv += 256) {
        int t = (pv >= sps[1]) + (pv >= sps[2]);
        prb[pv] = srs[t] + 22 * (pv - sps[t]);
    }
}

// deadMask[i] = alive weight (1 if alive, 0 if dead)
__global__ void k_deadmask(const void* __restrict__ dead,
                           const int* __restrict__ wsI, float* __restrict__ dm)
{
    int i = blockIdx.x * 256 + threadIdx.x;
    if (i >= NDEAD_) return;
    int mode = wsI[0];
    bool d;
    if (mode == 0)      d = ((const int*)dead)[i] != 0;
    else if (mode == 1) d = ((const float*)dead)[i] != 0.f;
    else                d = ((const unsigned char*)dead)[i] != 0;
    dm[i] = d ? 0.f : 1.f;
}

__global__ void k_denom(const int* __restrict__ pairIdx, const float* __restrict__ dm,
                        float* __restrict__ denf, float* __restrict__ denh)
{
    int pv = blockIdx.x * 256 + threadIdx.x;
    if (pv >= PV_) return;
    int p = pairIdx[pv];
    float sf = 0.f, sh = 0.f;
    if (p >= 0) {
        for (int e = 1; e < 12; ++e)  sf += dm[p * 22 + e];
        for (int e = 12; e < 22; ++e) sh += dm[p * 22 + e];
    }
    denf[pv] = fmaxf(sf, 1.f);
    denh[pv] = fmaxf(sh, 1.f);
}

// rowObs[rv] = obs row index for virtual row, or -1 (padding OR dead -> A row = 0)
__global__ void k_rowobs(const int* __restrict__ cnt, const int* __restrict__ ps,
                         const int* __restrict__ rs, const int* __restrict__ pairIdx,
                         const float* __restrict__ dm, int* __restrict__ rowObs)
{
    int rv = blockIdx.x * 256 + threadIdx.x;
    if (rv >= RV_) return;
    int t = (rv >= rs[1]) + (rv >= rs[2]);
    int local = rv - rs[t];
    int out = -1;
    if (local < 22 * cnt[t]) {
        int pl = local / 22;
        int e = local - pl * 22;
        int p = pairIdx[ps[t] + pl];
        if (p >= 0) {
            int oi = p * 22 + e;
            if (dm[oi] != 0.f) out = oi;   // dead -> -1 -> zero A row (matches ref masking)
        }
    }
    rowObs[rv] = out;
}

// ---------------------------------------------------------------------------
// Tiled fp32 GEMM: C[M x N] = op(A) @ B[type] + bias[type], optional relu.
// BM=BN=128, BK=16, 256 threads, 8x8 register tile per thread.
// Type per block from `starts` (2 ints: region starts of types 1 and 2;
// regions are 128-aligned so a tile never straddles types).
// ---------------------------------------------------------------------------
#define LDP 132  // padded LDS row: 2-way-max bank aliasing, keeps 16B alignment
template<bool GATHER, bool RELU>
__global__ __launch_bounds__(256, 2) void k_gemm(
    const float* __restrict__ A, int lda,
    const int* __restrict__ rowIdx,
    const float* __restrict__ B, int ldb, long Wstride,
    const float* __restrict__ bias, int biasStride,
    float* __restrict__ C, int ldc,
    const int* __restrict__ starts, int K)
{
    __shared__ float As[16][LDP];
    __shared__ float Bs[16][LDP];
    const int tid = threadIdx.x;
    const long rb = (long)blockIdx.x * 128;
    const int n0 = blockIdx.y * 128;
    const int s1 = starts[0], s2 = starts[1];
    const int t = (rb >= s1) + (rb >= s2);
    const float* Bt = B + (long)t * Wstride + n0;
    const float* biasT = bias + (long)t * biasStride + n0;

    // A loader: 2 rows x 4 cols (float4) per thread
    const int r0 = tid >> 2, r1 = r0 + 64;
    const int kq = (tid & 3) << 2;
    const float* pA0; const float* pA1;
    float m0 = 1.f, m1 = 1.f;
    if (GATHER) {
        int i0 = rowIdx[rb + r0], i1 = rowIdx[rb + r1];
        m0 = (i0 < 0) ? 0.f : 1.f; m1 = (i1 < 0) ? 0.f : 1.f;
        if (i0 < 0) i0 = 0; if (i1 < 0) i1 = 0;
        pA0 = A + (long)i0 * lda + kq;
        pA1 = A + (long)i1 * lda + kq;
    } else {
        pA0 = A + (rb + r0) * (long)lda + kq;
        pA1 = A + (rb + r1) * (long)lda + kq;
    }
    // B loader: 1 row x 8 cols per thread
    const int br = tid >> 4;
    const int bc = (tid & 15) * 8;
    const float* pB = Bt + (long)br * ldb + bc;

    const int tx = tid & 15, ty = tid >> 4;
    float acc[8][8];
#pragma unroll
    for (int i = 0; i < 8; ++i)
#pragma unroll
        for (int j = 0; j < 8; ++j) acc[i][j] = 0.f;

    for (int k0 = 0; k0 < K; k0 += 16) {
        float4 a0 = *(const float4*)(pA0 + k0);
        float4 a1 = *(const float4*)(pA1 + k0);
        float4 b0 = *(const float4*)(pB + (long)k0 * ldb);
        float4 b1 = *(const float4*)(pB + (long)k0 * ldb + 4);
        if (GATHER) {
            a0.x *= m0; a0.y *= m0; a0.z *= m0; a0.w *= m0;
            a1.x *= m1; a1.y *= m1; a1.z *= m1; a1.w *= m1;
        }
        __syncthreads();
        As[kq + 0][r0] = a0.x; As[kq + 1][r0] = a0.y; As[kq + 2][r0] = a0.z; As[kq + 3][r0] = a0.w;
        As[kq + 0][r1] = a1.x; As[kq + 1][r1] = a1.y; As[kq + 2][r1] = a1.z; As[kq + 3][r1] = a1.w;
        *(float4*)&Bs[br][bc] = b0;
        *(float4*)&Bs[br][bc + 4] = b1;
        __syncthreads();
#pragma unroll
        for (int k = 0; k < 16; ++k) {
            const float4 x0 = *(const float4*)&As[k][ty * 8];
            const float4 x1 = *(const float4*)&As[k][ty * 8 + 4];
            const float4 y0 = *(const float4*)&Bs[k][tx * 8];
            const float4 y1 = *(const float4*)&Bs[k][tx * 8 + 4];
            const float av[8] = {x0.x, x0.y, x0.z, x0.w, x1.x, x1.y, x1.z, x1.w};
            const float bv[8] = {y0.x, y0.y, y0.z, y0.w, y1.x, y1.y, y1.z, y1.w};
#pragma unroll
            for (int i = 0; i < 8; ++i)
#pragma unroll
                for (int j = 0; j < 8; ++j)
                    acc[i][j] = fmaf(av[i], bv[j], acc[i][j]);
        }
    }
    float bj[8];
#pragma unroll
    for (int j = 0; j < 8; ++j) bj[j] = biasT[tx * 8 + j];
#pragma unroll
    for (int i = 0; i < 8; ++i) {
        float* pC = C + (rb + ty * 8 + i) * (long)ldc + n0 + tx * 8;
        float4 o0, o1;
        o0.x = acc[i][0] + bj[0]; o0.y = acc[i][1] + bj[1];
        o0.z = acc[i][2] + bj[2]; o0.w = acc[i][3] + bj[3];
        o1.x = acc[i][4] + bj[4]; o1.y = acc[i][5] + bj[5];
        o1.z = acc[i][6] + bj[6]; o1.w = acc[i][7] + bj[7];
        if (RELU) {
            o0.x = fmaxf(o0.x, 0.f); o0.y = fmaxf(o0.y, 0.f);
            o0.z = fmaxf(o0.z, 0.f); o0.w = fmaxf(o0.w, 0.f);
            o1.x = fmaxf(o1.x, 0.f); o1.y = fmaxf(o1.y, 0.f);
            o1.z = fmaxf(o1.z, 0.f); o1.w = fmaxf(o1.w, 0.f);
        }
        *(float4*)pC = o0;
        *(float4*)(pC + 4) = o1;
    }
}

// poolf/poolh: masked mean of v over entities 1..11 / 12..21
__global__ void k_pool(const int* __restrict__ pairIdx, const int* __restrict__ prb,
                       const float* __restrict__ dm, const float* __restrict__ denf,
                       const float* __restrict__ denh, const float* __restrict__ v,
                       float* __restrict__ poolf, float* __restrict__ poolh)
{
    int pv = blockIdx.x, c = threadIdx.x;
    int p = pairIdx[pv];
    __shared__ float sw[22];
    if (p >= 0 && c < 22) sw[c] = dm[p * 22 + c];
    __syncthreads();
    float of = 0.f, oh = 0.f;
    if (p >= 0) {
        long base = prb[pv];
        float af = 0.f, ah = 0.f;
        for (int e = 1; e < 12; ++e)  af += sw[e] * v[(base + e) * 256 + c];
        for (int e = 12; e < 22; ++e) ah += sw[e] * v[(base + e) * 256 + c];
        of = af / denf[pv];
        oh = ah / denh[pv];
    }
    poolf[(long)pv * 256 + c] = of;
    poolh[(long)pv * 256 + c] = oh;
}

// poolzf/poolzh: masked mean of raw obs over entities 1..11 / 12..21
__global__ void k_poolz(const int* __restrict__ pairIdx, const float* __restrict__ dm,
                        const float* __restrict__ denf, const float* __restrict__ denh,
                        const float* __restrict__ obs,
                        float* __restrict__ poolzf, float* __restrict__ poolzh)
{
    int pv = blockIdx.x, tid = threadIdx.x;
    int p = pairIdx[pv];
    __shared__ float sw[22];
    if (p >= 0 && tid < 22) sw[tid] = dm[p * 22 + tid];
    __syncthreads();
    float rdf = 0.f, rdh = 0.f;
    if (p >= 0) { rdf = denf[pv]; rdh = denh[pv]; }
    for (int c = tid; c < 512; c += 256) {
        float zf = 0.f, zh = 0.f;
        if (p >= 0) {
            const float* ob = obs + (long)p * 22 * 512 + c;
            for (int e = 1; e < 12; ++e)  zf += sw[e] * ob[(long)e * 512];
            for (int e = 12; e < 22; ++e) zh += sw[e] * ob[(long)e * 512];
            zf /= rdf; zh /= rdh;
        }
        poolzf[(long)pv * 512 + c] = zf;
        poolzh[(long)pv * 512 + c] = zh;
    }
}

// Assemble XF = [vs, poolf, zs, poolzf], XH = [vs, poolh, zs, poolzh]  (1536 each)
__global__ void k_xasm(const int* __restrict__ pairIdx, const int* __restrict__ prb,
                       const float* __restrict__ dm, const float* __restrict__ v,
                       const float* __restrict__ poolf, const float* __restrict__ poolh,
                       const float* __restrict__ poolzf, const float* __restrict__ poolzh,
                       const float* __restrict__ obs,
                       float* __restrict__ XF, float* __restrict__ XH)
{
    int pv = blockIdx.x, c = threadIdx.x;
    int p = pairIdx[pv];
    float* xf = XF + (long)pv * 1536;
    float* xh = XH + (long)pv * 1536;
    if (p < 0) {
        for (int s = 0; s < 6; ++s) { xf[s * 256 + c] = 0.f; xh[s * 256 + c] = 0.f; }
        return;
    }
    long base = prb[pv];
    float vs = v[base * 256 + c];
    xf[c] = vs; xh[c] = vs;
    xf[256 + c] = poolf[(long)pv * 256 + c];
    xh[256 + c] = poolh[(long)pv * 256 + c];
    float w0 = dm[p * 22];
    float z0 = obs[(long)p * 22 * 512 + c] * w0;
    float z1 = obs[(long)p * 22 * 512 + 256 + c] * w0;
    xf[512 + c] = z0; xh[512 + c] = z0;
    xf[768 + c] = z1; xh[768 + c] = z1;
    xf[1024 + c] = poolzf[(long)pv * 512 + c];
    xf[1280 + c] = poolzf[(long)pv * 512 + 256 + c];
    xh[1024 + c] = poolzh[(long)pv * 512 + c];
    xh[1280 + c] = poolzh[(long)pv * 512 + 256 + c];
}

// Final: logits (L3) + argmax + log-softmax + value dot (V2); scatter to d_out.
__global__ void k_final(const float* __restrict__ g2, const float* __restrict__ vV,
                        const float* __restrict__ L3, const float* __restrict__ bL3,
                        const float* __restrict__ V2, const float* __restrict__ bV2,
                        const int* __restrict__ pairIdx, const int* __restrict__ ps,
                        float* __restrict__ out)
{
    int pv = blockIdx.x;
    int p = pairIdx[pv];
    if (p < 0) return;
    int lane = threadIdx.x;
    int t = (pv >= ps[1]) + (pv >= ps[2]);

    // value = vV . V2 + bV2
    const float* v2t = V2 + t * 256;
    const float* vv = vV + (long)pv * 256;
    float s = 0.f;
#pragma unroll
    for (int j = 0; j < 4; ++j) { int k = lane + 64 * j; s += vv[k] * v2t[k]; }
    for (int off = 32; off; off >>= 1) s += __shfl_down(s, off);

    // logits: lane i < 21 computes logit i
    const float* g = g2 + (long)pv * 128;
    float lg = -3.0e38f;
    if (lane < 21) {
        const float* l3t = L3 + t * 128 * 21 + lane;
        float a = bL3[t * 21 + lane];
        for (int k = 0; k < 128; ++k) a += g[k] * l3t[k * 21];
        lg = a;
    }
    // argmax (first-index tie-break)
    float mv = lg; int mi = (lane < 21) ? lane : 9999;
    for (int off = 32; off; off >>= 1) {
        float ov = __shfl_down(mv, off);
        int oi = __shfl_down(mi, off);
        if (ov > mv || (ov == mv && oi < mi)) { mv = ov; mi = oi; }
    }
    mv = __shfl(mv, 0); mi = __shfl(mi, 0);
    float e = (lane < 21) ? expf(lg - mv) : 0.f;
    for (int off = 32; off; off >>= 1) e += __shfl_down(e, off);
    if (lane == 0) {
        out[p] = (float)mi;                 // act (written as float; out buffer is f32)
        out[NP_ + p] = s + bV2[t];          // value
        out[2 * NP_ + p] = -logf(e);        // alp = logp at argmax
    }
}

// ---------------------------------------------------------------------------
extern "C" void kernel_launch(void* const* d_in, const int* in_sizes, int n_in,
                              void* d_out, int out_size, void* d_ws, size_t ws_size,
                              hipStream_t stream)
{
    const float* obs = (const float*)d_in[0];
    const int* hete = (const int*)d_in[1];
    const void* dead = d_in[2];
    const float* W1 = (const float*)d_in[3];  const float* b1 = (const float*)d_in[4];
    const float* W2 = (const float*)d_in[5];  const float* b2 = (const float*)d_in[6];
    const float* WCf = (const float*)d_in[7]; const float* bCf = (const float*)d_in[8];
    const float* WMf = (const float*)d_in[9]; const float* bMf = (const float*)d_in[10];
    const float* WCh = (const float*)d_in[11]; const float* bCh = (const float*)d_in[12];
    const float* WMh = (const float*)d_in[13]; const float* bMh = (const float*)d_in[14];
    const float* L1 = (const float*)d_in[15]; const float* bL1 = (const float*)d_in[16];
    const float* L2 = (const float*)d_in[17]; const float* bL2 = (const float*)d_in[18];
    const float* L3 = (const float*)d_in[19]; const float* bL3 = (const float*)d_in[20];
    const float* V1 = (const float*)d_in[21]; const float* bV1 = (const float*)d_in[22];
    const float* V2 = (const float*)d_in[23]; const float* bV2 = (const float*)d_in[24];
    float* out = (float*)d_out;

    // workspace carve-up (int region then float region); ~147 MB total
    int* wsI = (int*)d_ws;
    int* pairIdx = wsI + 16;
    int* prb = pairIdx + PV_;
    int* rowObs = prb + PV_;
    long fbase = ((16L + PV_ + PV_ + RV_) + 63) & ~63L;
    float* wsF = (float*)d_ws;
    float* dm = wsF + fbase;
    float* denf = dm + NDEAD_;
    float* denh = denf + PV_;
    float* poolf = denh + PV_;
    float* poolh = poolf + (long)PV_ * 256;
    float* regA = poolh + (long)PV_ * 256;           // RV_*256 floats
    float* regB = regA + (long)RV_ * 256;            // RV_*256 floats
    // regA: h1 first, then (after gemm2) XF/XH/poolz overlays
    float* h1 = regA;
    float* XF = regA;
    float* XH = XF + (long)PV_ * 1536;
    float* poolzf = XH + (long)PV_ * 1536;
    float* poolzh = poolzf + (long)PV_ * 512;
    // regB: v first, then head activations overlay
    float* v = regB;
    float* vC = regB;
    float* vM = vC + (long)PV_ * 512;
    float* g1 = vM + (long)PV_ * 512;
    float* g2 = g1 + (long)PV_ * 256;
    float* vV = g2 + (long)PV_ * 128;

    k_bucket<<<1, 256, 0, stream>>>((const unsigned*)dead, hete, wsI);
    k_deadmask<<<264, 256, 0, stream>>>(dead, wsI, dm);
    k_denom<<<14, 256, 0, stream>>>(pairIdx, dm, denf, denh);
    k_rowobs<<<266, 256, 0, stream>>>(wsI + 1, wsI + 4, wsI + 8, pairIdx, dm, rowObs);

    // phase 1: h1 = relu(obs@W1+b1); v = h1@W2+b2   (rows bucketed by type)
    k_gemm<true, true><<<dim3(532, 2), 256, 0, stream>>>(
        obs, 512, rowObs, W1, 256, 512L * 256, b1, 256, h1, 256, wsI + 9, 512);
    k_gemm<false, false><<<dim3(532, 2), 256, 0, stream>>>(
        h1, 256, nullptr, W2, 256, 256L * 256, b2, 256, v, 256, wsI + 9, 256);

    k_pool<<<PV_, 256, 0, stream>>>(pairIdx, prb, dm, denf, denh, v, poolf, poolh);
    k_poolz<<<PV_, 256, 0, stream>>>(pairIdx, dm, denf, denh, obs, poolzf, poolzh);
    k_xasm<<<PV_, 256, 0, stream>>>(pairIdx, prb, dm, v, poolf, poolh, poolzf, poolzh, obs, XF, XH);

    // heads (pair-space GEMMs, type from ps)
    k_gemm<false, true><<<dim3(27, 2), 256, 0, stream>>>(
        XF, 1536, nullptr, WCf, 256, 512L * 256, bCf, 256, vC, 512, wsI + 5, 512);
    k_gemm<false, true><<<dim3(27, 2), 256, 0, stream>>>(
        XH, 1536, nullptr, WCh, 256, 512L * 256, bCh, 256, vC + 256, 512, wsI + 5, 512);
    k_gemm<false, true><<<dim3(27, 2), 256, 0, stream>>>(
        XF, 1536, nullptr, WMf, 256, 1536L * 256, bMf, 256, vM, 512, wsI + 5, 1536);
    k_gemm<false, true><<<dim3(27, 2), 256, 0, stream>>>(
        XH, 1536, nullptr, WMh, 256, 1536L * 256, bMh, 256, vM + 256, 512, wsI + 5, 1536);
    k_gemm<false, true><<<dim3(27, 2), 256, 0, stream>>>(
        vC, 512, nullptr, L1, 256, 512L * 256, bL1, 256, g1, 256, wsI + 5, 512);
    k_gemm<false, true><<<dim3(27, 1), 256, 0, stream>>>(
        g1, 256, nullptr, L2, 128, 256L * 128, bL2, 128, g2, 128, wsI + 5, 256);
    k_gemm<false, true><<<dim3(27, 2), 256, 0, stream>>>(
        vM, 512, nullptr, V1, 256, 512L * 256, bV1, 256, vV, 256, wsI + 5, 512);

    k_final<<<PV_, 64, 0, stream>>>(g2, vV, L3, bL3, V2, bV2, pairIdx, wsI + 4, out);
    (void)in_sizes; (void)n_in; (void)out_size; (void)ws_size;
}

// Round 2
// 898.177 us; speedup vs baseline: 1.5171x; 1.5171x over previous
//
#include <hip/hip_runtime.h>
#include <cstdint>

// Problem constants
#define T_ 64
#define A_ 48
#define NP_ 3072      // T*A pairs
#define E_ 22
#define RAW_ 512
#define H_ 256
#define NACT_ 21
#define NTP_ 3
#define PV_ 3456      // padded virtual pair rows (27 tiles of 128)
#define RV_ 68096     // padded virtual entity rows (532 tiles of 128)
#define NDEAD_ 67584  // NP_*E_

// ---------------------------------------------------------------------------
// K_bucket: sniff dead dtype, count pairs per type, build bucketed pair list.
// wsI layout: [0]=mode, [1..3]=cnt, [4..6]=ps, [8..10]=rs,
//             [16..16+PV)=pairIdx, then prb[PV]
// ---------------------------------------------------------------------------
__global__ void k_bucket(const unsigned* __restrict__ deadRaw,
                         const int* __restrict__ hete, int* __restrict__ wsI)
{
    __shared__ int fl[2];
    __shared__ int sc[3], cur[3], sps[3], srs[3];
    int tid = threadIdx.x;
    if (tid < 2) fl[tid] = 0;
    if (tid < 3) { sc[tid] = 0; cur[tid] = 0; }
    __syncthreads();
    int ni = 0, nf = 0;
    for (int i = tid; i < 1024; i += 256) {
        unsigned w = deadRaw[i];
        if (w > 1u) ni = 1;
        if (w != 0u && w != 0x3F800000u) nf = 1;
    }
    if (ni) atomicOr(&fl[0], 1);
    if (nf) atomicOr(&fl[1], 1);
    for (int p = tid; p < NP_; p += 256) atomicAdd(&sc[hete[p]], 1);
    __syncthreads();
    if (tid == 0) {
        int c0 = sc[0], c1 = sc[1], c2 = sc[2];
        int p1 = (c0 + 127) & ~127;
        int p2 = p1 + ((c1 + 127) & ~127);
        sps[0] = 0; sps[1] = p1; sps[2] = p2;
        int r1 = (22 * c0 + 127) & ~127;
        int r2 = r1 + ((22 * c1 + 127) & ~127);
        srs[0] = 0; srs[1] = r1; srs[2] = r2;
        wsI[0] = fl[0] ? (fl[1] ? 2 : 1) : 0;  // 0=int32,1=float32,2=byte
        wsI[1] = c0; wsI[2] = c1; wsI[3] = c2;
        wsI[4] = 0; wsI[5] = p1; wsI[6] = p2;
        wsI[8] = 0; wsI[9] = r1; wsI[10] = r2;
    }
    __syncthreads();
    int* pairIdx = wsI + 16;
    int* prb = pairIdx + PV_;
    for (int pv = tid; pv < PV_; pv += 256) pairIdx[pv] = -1;
    __syncthreads();
    for (int p = tid; p < NP_; p += 256) {
        int t = hete[p];
        int pos = atomicAdd(&cur[t], 1);
        pairIdx[sps[t] + pos] = p;
    }
    for (int pv = tid; pv < PV_; pv += 256) {
        int t = (pv >= sps[1]) + (pv >= sps[2]);
        prb[pv] = srs[t] + 22 * (pv - sps[t]);
    }
}

__global__ void k_deadmask(const void* __restrict__ dead,
                           const int* __restrict__ wsI, float* __restrict__ dm)
{
    int i = blockIdx.x * 256 + threadIdx.x;
    if (i >= NDEAD_) return;
    int mode = wsI[0];
    bool d;
    if (mode == 0)      d = ((const int*)dead)[i] != 0;
    else if (mode == 1) d = ((const float*)dead)[i] != 0.f;
    else                d = ((const unsigned char*)dead)[i] != 0;
    dm[i] = d ? 0.f : 1.f;
}

// rowObs[rv] = obs row index for virtual row, or -1 (padding OR dead -> zero A row)
__global__ void k_rowobs(const int* __restrict__ cnt, const int* __restrict__ ps,
                         const int* __restrict__ rs, const int* __restrict__ pairIdx,
                         const float* __restrict__ dm, int* __restrict__ rowObs)
{
    int rv = blockIdx.x * 256 + threadIdx.x;
    if (rv >= RV_) return;
    int t = (rv >= rs[1]) + (rv >= rs[2]);
    int local = rv - rs[t];
    int out = -1;
    if (local < 22 * cnt[t]) {
        int pl = local / 22;
        int e = local - pl * 22;
        int p = pairIdx[ps[t] + pl];
        if (p >= 0) {
            int oi = p * 22 + e;
            if (dm[oi] != 0.f) out = oi;
        }
    }
    rowObs[rv] = out;
}

// ---------------------------------------------------------------------------
// Big tiled fp32 GEMM (phase 1): BM=BN=128, BK=16, 8x8/thread.
// ---------------------------------------------------------------------------
#define LDP 132
template<bool GATHER, bool RELU>
__global__ __launch_bounds__(256, 2) void k_gemm(
    const float* __restrict__ A, int lda,
    const int* __restrict__ rowIdx,
    const float* __restrict__ B, int ldb, long Wstride,
    const float* __restrict__ bias, int biasStride,
    float* __restrict__ C, int ldc,
    const int* __restrict__ starts, int K)
{
    __shared__ float As[16][LDP];
    __shared__ float Bs[16][LDP];
    const int tid = threadIdx.x;
    const long rb = (long)blockIdx.x * 128;
    const int n0 = blockIdx.y * 128;
    const int s1 = starts[0], s2 = starts[1];
    const int t = (rb >= s1) + (rb >= s2);
    const float* Bt = B + (long)t * Wstride + n0;
    const float* biasT = bias + (long)t * biasStride + n0;

    const int r0 = tid >> 2, r1 = r0 + 64;
    const int kq = (tid & 3) << 2;
    const float* pA0; const float* pA1;
    float m0 = 1.f, m1 = 1.f;
    if (GATHER) {
        int i0 = rowIdx[rb + r0], i1 = rowIdx[rb + r1];
        m0 = (i0 < 0) ? 0.f : 1.f; m1 = (i1 < 0) ? 0.f : 1.f;
        if (i0 < 0) i0 = 0; if (i1 < 0) i1 = 0;
        pA0 = A + (long)i0 * lda + kq;
        pA1 = A + (long)i1 * lda + kq;
    } else {
        pA0 = A + (rb + r0) * (long)lda + kq;
        pA1 = A + (rb + r1) * (long)lda + kq;
    }
    const int br = tid >> 4;
    const int bc = (tid & 15) * 8;
    const float* pB = Bt + (long)br * ldb + bc;

    const int tx = tid & 15, ty = tid >> 4;
    float acc[8][8];
#pragma unroll
    for (int i = 0; i < 8; ++i)
#pragma unroll
        for (int j = 0; j < 8; ++j) acc[i][j] = 0.f;

    for (int k0 = 0; k0 < K; k0 += 16) {
        float4 a0 = *(const float4*)(pA0 + k0);
        float4 a1 = *(const float4*)(pA1 + k0);
        float4 b0 = *(const float4*)(pB + (long)k0 * ldb);
        float4 b1 = *(const float4*)(pB + (long)k0 * ldb + 4);
        if (GATHER) {
            a0.x *= m0; a0.y *= m0; a0.z *= m0; a0.w *= m0;
            a1.x *= m1; a1.y *= m1; a1.z *= m1; a1.w *= m1;
        }
        __syncthreads();
        As[kq + 0][r0] = a0.x; As[kq + 1][r0] = a0.y; As[kq + 2][r0] = a0.z; As[kq + 3][r0] = a0.w;
        As[kq + 0][r1] = a1.x; As[kq + 1][r1] = a1.y; As[kq + 2][r1] = a1.z; As[kq + 3][r1] = a1.w;
        *(float4*)&Bs[br][bc] = b0;
        *(float4*)&Bs[br][bc + 4] = b1;
        __syncthreads();
#pragma unroll
        for (int k = 0; k < 16; ++k) {
            const float4 x0 = *(const float4*)&As[k][ty * 8];
            const float4 x1 = *(const float4*)&As[k][ty * 8 + 4];
            const float4 y0 = *(const float4*)&Bs[k][tx * 8];
            const float4 y1 = *(const float4*)&Bs[k][tx * 8 + 4];
            const float av[8] = {x0.x, x0.y, x0.z, x0.w, x1.x, x1.y, x1.z, x1.w};
            const float bv[8] = {y0.x, y0.y, y0.z, y0.w, y1.x, y1.y, y1.z, y1.w};
#pragma unroll
            for (int i = 0; i < 8; ++i)
#pragma unroll
                for (int j = 0; j < 8; ++j)
                    acc[i][j] = fmaf(av[i], bv[j], acc[i][j]);
        }
    }
    float bj[8];
#pragma unroll
    for (int j = 0; j < 8; ++j) bj[j] = biasT[tx * 8 + j];
#pragma unroll
    for (int i = 0; i < 8; ++i) {
        float* pC = C + (rb + ty * 8 + i) * (long)ldc + n0 + tx * 8;
        float4 o0, o1;
        o0.x = acc[i][0] + bj[0]; o0.y = acc[i][1] + bj[1];
        o0.z = acc[i][2] + bj[2]; o0.w = acc[i][3] + bj[3];
        o1.x = acc[i][4] + bj[4]; o1.y = acc[i][5] + bj[5];
        o1.z = acc[i][6] + bj[6]; o1.w = acc[i][7] + bj[7];
        if (RELU) {
            o0.x = fmaxf(o0.x, 0.f); o0.y = fmaxf(o0.y, 0.f);
            o0.z = fmaxf(o0.z, 0.f); o0.w = fmaxf(o0.w, 0.f);
            o1.x = fmaxf(o1.x, 0.f); o1.y = fmaxf(o1.y, 0.f);
            o1.z = fmaxf(o1.z, 0.f); o1.w = fmaxf(o1.w, 0.f);
        }
        *(float4*)pC = o0;
        *(float4*)(pC + 4) = o1;
    }
}

// ---------------------------------------------------------------------------
// k_prep: per pair — denom, v-pool, z-pool, assemble XF/XH (1536 each).
// XF = [vs, poolf, zs(512), poolzf(512)], XH = [vs, poolh, zs, poolzh]
// ---------------------------------------------------------------------------
__global__ __launch_bounds__(256) void k_prep(
    const int* __restrict__ pairIdx, const int* __restrict__ prb,
    const float* __restrict__ dm, const float* __restrict__ v,
    const float* __restrict__ obs,
    float* __restrict__ XF, float* __restrict__ XH)
{
    int pv = blockIdx.x, c = threadIdx.x;
    int p = pairIdx[pv];
    float* xf = XF + (long)pv * 1536;
    float* xh = XH + (long)pv * 1536;
    if (p < 0) {
        for (int s = 0; s < 6; ++s) { xf[s * 256 + c] = 0.f; xh[s * 256 + c] = 0.f; }
        return;
    }
    __shared__ float sw[22];
    if (c < 22) sw[c] = dm[p * 22 + c];
    __syncthreads();
    float denf = 0.f, denh = 0.f;
    for (int e = 1; e < 12; ++e)  denf += sw[e];
    for (int e = 12; e < 22; ++e) denh += sw[e];
    denf = 1.f / fmaxf(denf, 1.f);
    denh = 1.f / fmaxf(denh, 1.f);

    long base = prb[pv];
    // vs (entity 0, unmasked per reference)
    float vs = v[base * 256 + c];
    xf[c] = vs; xh[c] = vs;
    // v-pools
    float af = 0.f, ah = 0.f;
    for (int e = 1; e < 12; ++e)  af += sw[e] * v[(base + e) * 256 + c];
    for (int e = 12; e < 22; ++e) ah += sw[e] * v[(base + e) * 256 + c];
    xf[256 + c] = af * denf;
    xh[256 + c] = ah * denh;
    // zs (entity 0 raw obs, masked by dead[0])
    const float* ob = obs + (long)p * 22 * 512;
    float w0 = sw[0];
    float z0 = ob[c] * w0;
    float z1 = ob[256 + c] * w0;
    xf[512 + c] = z0; xh[512 + c] = z0;
    xf[768 + c] = z1; xh[768 + c] = z1;
    // z-pools (512 cols, two per thread)
#pragma unroll
    for (int half = 0; half < 2; ++half) {
        int c2 = c + half * 256;
        float zf = 0.f, zh = 0.f;
        for (int e = 1; e < 12; ++e)  zf += sw[e] * ob[(long)e * 512 + c2];
        for (int e = 12; e < 22; ++e) zh += sw[e] * ob[(long)e * 512 + c2];
        xf[1024 + c2] = zf * denf;
        xh[1024 + c2] = zh * denh;
    }
}

// ---------------------------------------------------------------------------
// Head GEMM: BM=64, BN=128, two problems batched on blockIdx.z; relu always.
// ---------------------------------------------------------------------------
__global__ __launch_bounds__(256) void k_hgemm(
    const float* __restrict__ A0, const float* __restrict__ A1, int lda,
    const float* __restrict__ B0, const float* __restrict__ B1, long Wstride,
    const float* __restrict__ bias0, const float* __restrict__ bias1,
    float* __restrict__ C0, float* __restrict__ C1, int ldc,
    int coff0, int coff1, int K, const int* __restrict__ starts)
{
    __shared__ float As[16][68];
    __shared__ float Bs[16][132];
    const int tid = threadIdx.x;
    const int z = blockIdx.z;
    const float* A = z ? A1 : A0;
    const float* B = z ? B1 : B0;
    const float* bias = z ? bias1 : bias0;
    float* C = z ? C1 : C0;
    const int coff = z ? coff1 : coff0;
    const long rb = (long)blockIdx.x * 64;
    const int n0 = blockIdx.y * 128;
    const int t = (rb >= starts[0]) + (rb >= starts[1]);
    const float* Bt = B + (long)t * Wstride + n0;
    const float* biasT = bias + (long)t * 256 + n0;

    // A loader: 1 row x float4 per thread (64 rows x 16 k)
    const int ar = tid >> 2;
    const int kq = (tid & 3) << 2;
    const float* pA = A + (rb + ar) * (long)lda + kq;
    // B loader: 1 row x 8 cols
    const int br = tid >> 4;
    const int bc = (tid & 15) * 8;
    const float* pB = Bt + (long)br * 256 + bc;

    const int tx = tid & 15, ty = tid >> 4;
    float acc[4][8];
#pragma unroll
    for (int i = 0; i < 4; ++i)
#pragma unroll
        for (int j = 0; j < 8; ++j) acc[i][j] = 0.f;

    for (int k0 = 0; k0 < K; k0 += 16) {
        float4 a0 = *(const float4*)(pA + k0);
        float4 b0 = *(const float4*)(pB + (long)k0 * 256);
        float4 b1 = *(const float4*)(pB + (long)k0 * 256 + 4);
        __syncthreads();
        As[kq + 0][ar] = a0.x; As[kq + 1][ar] = a0.y; As[kq + 2][ar] = a0.z; As[kq + 3][ar] = a0.w;
        *(float4*)&Bs[br][bc] = b0;
        *(float4*)&Bs[br][bc + 4] = b1;
        __syncthreads();
#pragma unroll
        for (int k = 0; k < 16; ++k) {
            const float4 x0 = *(const float4*)&As[k][ty * 4];
            const float4 y0 = *(const float4*)&Bs[k][tx * 8];
            const float4 y1 = *(const float4*)&Bs[k][tx * 8 + 4];
            const float av[4] = {x0.x, x0.y, x0.z, x0.w};
            const float bv[8] = {y0.x, y0.y, y0.z, y0.w, y1.x, y1.y, y1.z, y1.w};
#pragma unroll
            for (int i = 0; i < 4; ++i)
#pragma unroll
                for (int j = 0; j < 8; ++j)
                    acc[i][j] = fmaf(av[i], bv[j], acc[i][j]);
        }
    }
    float bj[8];
#pragma unroll
    for (int j = 0; j < 8; ++j) bj[j] = biasT[tx * 8 + j];
#pragma unroll
    for (int i = 0; i < 4; ++i) {
        float* pC = C + (rb + ty * 4 + i) * (long)ldc + coff + n0 + tx * 8;
        float4 o0, o1;
        o0.x = fmaxf(acc[i][0] + bj[0], 0.f); o0.y = fmaxf(acc[i][1] + bj[1], 0.f);
        o0.z = fmaxf(acc[i][2] + bj[2], 0.f); o0.w = fmaxf(acc[i][3] + bj[3], 0.f);
        o1.x = fmaxf(acc[i][4] + bj[4], 0.f); o1.y = fmaxf(acc[i][5] + bj[5], 0.f);
        o1.z = fmaxf(acc[i][6] + bj[6], 0.f); o1.w = fmaxf(acc[i][7] + bj[7], 0.f);
        *(float4*)pC = o0;
        *(float4*)(pC + 4) = o1;
    }
}

// ---------------------------------------------------------------------------
// Final: L2 layer fused + logits + argmax + log-softmax + value dot; scatter.
// 128 threads/block, one block per pv.
// ---------------------------------------------------------------------------
__global__ __launch_bounds__(128) void k_final(
    const float* __restrict__ g1, const float* __restrict__ vV,
    const float* __restrict__ L2, const float* __restrict__ bL2,
    const float* __restrict__ L3, const float* __restrict__ bL3,
    const float* __restrict__ V2, const float* __restrict__ bV2,
    const int* __restrict__ pairIdx, const int* __restrict__ ps,
    float* __restrict__ out)
{
    int pv = blockIdx.x;
    int p = pairIdx[pv];
    if (p < 0) return;
    int c = threadIdx.x;
    int t = (pv >= ps[1]) + (pv >= ps[2]);

    __shared__ float sg1[256], sg2[128], sval[2];
    const float* g1p = g1 + (long)pv * 256;
    sg1[c] = g1p[c];
    sg1[c + 128] = g1p[c + 128];

    // value partials
    const float* vv = vV + (long)pv * 256;
    const float* v2t = V2 + t * 256;
    float s = vv[c] * v2t[c] + vv[c + 128] * v2t[c + 128];
    for (int off = 32; off; off >>= 1) s += __shfl_down(s, off);
    if ((c & 63) == 0) sval[c >> 6] = s;
    __syncthreads();

    // g2 = relu(g1 @ L2 + bL2)   (thread c -> column c of 128)
    const float* l2 = L2 + (long)t * 256 * 128 + c;
    float a = bL2[t * 128 + c];
#pragma unroll 8
    for (int k = 0; k < 256; ++k) a = fmaf(sg1[k], l2[(long)k * 128], a);
    sg2[c] = fmaxf(a, 0.f);
    __syncthreads();

    if (c < 64) {
        float lg = -3.0e38f;
        if (c < 21) {
            const float* l3t = L3 + (long)t * 128 * 21 + c;
            float acc = bL3[t * 21 + c];
            for (int k = 0; k < 128; ++k) acc = fmaf(sg2[k], l3t[k * 21], acc);
            lg = acc;
        }
        float mv = lg; int mi = (c < 21) ? c : 9999;
        for (int off = 32; off; off >>= 1) {
            float ov = __shfl_down(mv, off);
            int oi = __shfl_down(mi, off);
            if (ov > mv || (ov == mv && oi < mi)) { mv = ov; mi = oi; }
        }
        mv = __shfl(mv, 0); mi = __shfl(mi, 0);
        float e = (c < 21) ? expf(lg - mv) : 0.f;
        for (int off = 32; off; off >>= 1) e += __shfl_down(e, off);
        if (c == 0) {
            out[p] = (float)mi;
            out[NP_ + p] = sval[0] + sval[1] + bV2[t];
            out[2 * NP_ + p] = -logf(e);
        }
    }
}

// ---------------------------------------------------------------------------
extern "C" void kernel_launch(void* const* d_in, const int* in_sizes, int n_in,
                              void* d_out, int out_size, void* d_ws, size_t ws_size,
                              hipStream_t stream)
{
    const float* obs = (const float*)d_in[0];
    const int* hete = (const int*)d_in[1];
    const void* dead = d_in[2];
    const float* W1 = (const float*)d_in[3];  const float* b1 = (const float*)d_in[4];
    const float* W2 = (const float*)d_in[5];  const float* b2 = (const float*)d_in[6];
    const float* WCf = (const float*)d_in[7]; const float* bCf = (const float*)d_in[8];
    const float* WMf = (const float*)d_in[9]; const float* bMf = (const float*)d_in[10];
    const float* WCh = (const float*)d_in[11]; const float* bCh = (const float*)d_in[12];
    const float* WMh = (const float*)d_in[13]; const float* bMh = (const float*)d_in[14];
    const float* L1 = (const float*)d_in[15]; const float* bL1 = (const float*)d_in[16];
    const float* L2 = (const float*)d_in[17]; const float* bL2 = (const float*)d_in[18];
    const float* L3 = (const float*)d_in[19]; const float* bL3 = (const float*)d_in[20];
    const float* V1 = (const float*)d_in[21]; const float* bV1 = (const float*)d_in[22];
    const float* V2 = (const float*)d_in[23]; const float* bV2 = (const float*)d_in[24];
    float* out = (float*)d_out;

    int* wsI = (int*)d_ws;
    int* pairIdx = wsI + 16;
    int* prb = pairIdx + PV_;
    int* rowObs = prb + PV_;
    long fbase = ((16L + PV_ + PV_ + RV_) + 63) & ~63L;
    float* wsF = (float*)d_ws;
    float* dm = wsF + fbase;
    float* regA = dm + NDEAD_;                       // RV_*256 floats
    float* regB = regA + (long)RV_ * 256;            // RV_*256 floats
    // regA: h1 first, then XF/XH overlay (h1 dead after gemm2)
    float* h1 = regA;
    float* XF = regA;
    float* XH = XF + (long)PV_ * 1536;
    // regB: v first, then head activations overlay (v dead after k_prep)
    float* v = regB;
    float* vC = regB;
    float* vM = vC + (long)PV_ * 512;
    float* g1 = vM + (long)PV_ * 512;
    float* vV = g1 + (long)PV_ * 256;

    k_bucket<<<1, 256, 0, stream>>>((const unsigned*)dead, hete, wsI);
    k_deadmask<<<264, 256, 0, stream>>>(dead, wsI, dm);
    k_rowobs<<<266, 256, 0, stream>>>(wsI + 1, wsI + 4, wsI + 8, pairIdx, dm, rowObs);

    // phase 1: h1 = relu(obs@W1+b1); v = h1@W2+b2   (rows bucketed by type)
    k_gemm<true, true><<<dim3(532, 2), 256, 0, stream>>>(
        obs, 512, rowObs, W1, 256, 512L * 256, b1, 256, h1, 256, wsI + 9, 512);
    k_gemm<false, false><<<dim3(532, 2), 256, 0, stream>>>(
        h1, 256, nullptr, W2, 256, 256L * 256, b2, 256, v, 256, wsI + 9, 256);

    k_prep<<<PV_, 256, 0, stream>>>(pairIdx, prb, dm, v, obs, XF, XH);

    // heads, batched in pairs on blockIdx.z
    // H1: vC = [relu(XF@WCf+bCf) | relu(XH@WCh+bCh)]      K=512
    k_hgemm<<<dim3(PV_ / 64, 2, 2), 256, 0, stream>>>(
        XF, XH, 1536, WCf, WCh, 512L * 256, bCf, bCh, vC, vC, 512, 0, 256, 512, wsI + 5);
    // H2: vM = [relu(XF@WMf+bMf) | relu(XH@WMh+bMh)]      K=1536
    k_hgemm<<<dim3(PV_ / 64, 2, 2), 256, 0, stream>>>(
        XF, XH, 1536, WMf, WMh, 1536L * 256, bMf, bMh, vM, vM, 512, 0, 256, 1536, wsI + 5);
    // H3: g1 = relu(vC@L1+bL1); vV = relu(vM@V1+bV1)       K=512
    k_hgemm<<<dim3(PV_ / 64, 2, 2), 256, 0, stream>>>(
        vC, vM, 512, L1, V1, 512L * 256, bL1, bV1, g1, vV, 256, 0, 0, 512, wsI + 5);

    k_final<<<PV_, 128, 0, stream>>>(g1, vV, L2, bL2, L3, bL3, V2, bV2,
                                     pairIdx, wsI + 4, out);
    (void)in_sizes; (void)n_in; (void)out_size; (void)ws_size;
}

// Round 3
// 614.277 us; speedup vs baseline: 2.2183x; 1.4622x over previous
//
#include <hip/hip_runtime.h>
#include <cstdint>

// Problem constants
#define T_ 64
#define A_ 48
#define NP_ 3072      // T*A pairs
#define E_ 22
#define RAW_ 512
#define H_ 256
#define NACT_ 21
#define NTP_ 3
#define PV_ 3456      // padded virtual pair rows (27 tiles of 128)
#define RV_ 68096     // padded virtual entity rows (532 tiles of 128)
#define NDEAD_ 67584  // NP_*E_

typedef unsigned short u16;
typedef __attribute__((ext_vector_type(8))) short short8;
typedef __attribute__((ext_vector_type(4))) short short4v;
typedef __attribute__((ext_vector_type(4))) float floatx4;

__device__ __forceinline__ u16 f2bf(float x) {
    unsigned u = __float_as_uint(x);
    unsigned r = (u + 0x7FFFu + ((u >> 16) & 1u)) >> 16;
    return (u16)r;
}
__device__ __forceinline__ float bf2f(u16 h) {
    return __uint_as_float(((unsigned)h) << 16);
}

// ---------------------------------------------------------------------------
// K_bucket: sniff dead dtype, count pairs per type, build bucketed pair list.
// wsI layout: [0]=mode, [1..3]=cnt, [4..6]=ps, [8..10]=rs,
//             [16..16+PV)=pairIdx, then prb[PV]
// ---------------------------------------------------------------------------
__global__ void k_bucket(const unsigned* __restrict__ deadRaw,
                         const int* __restrict__ hete, int* __restrict__ wsI)
{
    __shared__ int fl[2];
    __shared__ int sc[3], cur[3], sps[3], srs[3];
    int tid = threadIdx.x;
    if (tid < 2) fl[tid] = 0;
    if (tid < 3) { sc[tid] = 0; cur[tid] = 0; }
    __syncthreads();
    int ni = 0, nf = 0;
    for (int i = tid; i < 1024; i += 256) {
        unsigned w = deadRaw[i];
        if (w > 1u) ni = 1;
        if (w != 0u && w != 0x3F800000u) nf = 1;
    }
    if (ni) atomicOr(&fl[0], 1);
    if (nf) atomicOr(&fl[1], 1);
    for (int p = tid; p < NP_; p += 256) atomicAdd(&sc[hete[p]], 1);
    __syncthreads();
    if (tid == 0) {
        int c0 = sc[0], c1 = sc[1], c2 = sc[2];
        int p1 = (c0 + 127) & ~127;
        int p2 = p1 + ((c1 + 127) & ~127);
        sps[0] = 0; sps[1] = p1; sps[2] = p2;
        int r1 = (22 * c0 + 127) & ~127;
        int r2 = r1 + ((22 * c1 + 127) & ~127);
        srs[0] = 0; srs[1] = r1; srs[2] = r2;
        wsI[0] = fl[0] ? (fl[1] ? 2 : 1) : 0;  // 0=int32,1=float32,2=byte
        wsI[1] = c0; wsI[2] = c1; wsI[3] = c2;
        wsI[4] = 0; wsI[5] = p1; wsI[6] = p2;
        wsI[8] = 0; wsI[9] = r1; wsI[10] = r2;
    }
    __syncthreads();
    int* pairIdx = wsI + 16;
    int* prb = pairIdx + PV_;
    for (int pv = tid; pv < PV_; pv += 256) pairIdx[pv] = -1;
    __syncthreads();
    for (int p = tid; p < NP_; p += 256) {
        int t = hete[p];
        int pos = atomicAdd(&cur[t], 1);
        pairIdx[sps[t] + pos] = p;
    }
    for (int pv = tid; pv < PV_; pv += 256) {
        int t = (pv >= sps[1]) + (pv >= sps[2]);
        prb[pv] = srs[t] + 22 * (pv - sps[t]);
    }
}

__global__ void k_deadmask(const void* __restrict__ dead,
                           const int* __restrict__ wsI, float* __restrict__ dm)
{
    int i = blockIdx.x * 256 + threadIdx.x;
    if (i >= NDEAD_) return;
    int mode = wsI[0];
    bool d;
    if (mode == 0)      d = ((const int*)dead)[i] != 0;
    else if (mode == 1) d = ((const float*)dead)[i] != 0.f;
    else                d = ((const unsigned char*)dead)[i] != 0;
    dm[i] = d ? 0.f : 1.f;
}

// rowObs[rv] = obs row index for virtual row, or -1 (padding OR dead -> zero A row)
__global__ void k_rowobs(const int* __restrict__ cnt, const int* __restrict__ ps,
                         const int* __restrict__ rs, const int* __restrict__ pairIdx,
                         const float* __restrict__ dm, int* __restrict__ rowObs)
{
    int rv = blockIdx.x * 256 + threadIdx.x;
    if (rv >= RV_) return;
    int t = (rv >= rs[1]) + (rv >= rs[2]);
    int local = rv - rs[t];
    int out = -1;
    if (local < 22 * cnt[t]) {
        int pl = local / 22;
        int e = local - pl * 22;
        int p = pairIdx[ps[t] + pl];
        if (p >= 0) {
            int oi = p * 22 + e;
            if (dm[oi] != 0.f) out = oi;
        }
    }
    rowObs[rv] = out;
}

// ---------------------------------------------------------------------------
// k_wconv: W[t][k][n] (fp32, n-width 256) -> WT_hi/WT_lo[t][n][k] (bf16 split)
// block = one (t, kc) pair; thread = n. Coalesced reads; 16B scattered writes.
// ---------------------------------------------------------------------------
__global__ void k_wconv(const float* __restrict__ W, u16* __restrict__ Hi,
                        u16* __restrict__ Lo, int K)
{
    int K8 = K >> 3;
    int kc = blockIdx.x % K8;
    int t  = blockIdx.x / K8;
    int n  = threadIdx.x;
    const float* w = W + (long)t * K * 256 + n;
    short8 hv, lv;
#pragma unroll
    for (int j = 0; j < 8; ++j) {
        float x = w[(long)(kc * 8 + j) * 256];
        u16 hh = f2bf(x);
        hv[j] = (short)hh;
        lv[j] = (short)f2bf(x - bf2f(hh));
    }
    long o = ((long)t * 256 + n) * K + kc * 8;
    *(short8*)(Hi + o) = hv;
    *(short8*)(Lo + o) = lv;
}

// ---------------------------------------------------------------------------
// MFMA GEMM via bf16x3 split: C = op(A) @ B[type] + bias[type], optional relu.
// Tile 128x128, BK=32, 256 threads (4 waves, each 64x64 = 4x4 frags of 16x16).
// A fp32 (optional row-gather+mask), converted to bf16 hi/lo on the fly.
// B pre-split bf16 hi/lo, layout [t][n][k] (k contiguous), N fixed 256.
// blockIdx.z selects problem pair (batched head launches).
// Verified layouts (learn_hip m89/m120): A-frag A[m=lane&15][k=quad*8+j],
// B-frag B[k=quad*8+j][n=lane&15], D col=lane&15 row=quad*4+reg.
// ---------------------------------------------------------------------------
#define AST 40  // LDS row stride in shorts: 32 k + 8 pad -> 2-way banks (free)
template<bool GATHER, bool RELU>
__global__ __launch_bounds__(256) void k_mgemm(
    const float* __restrict__ A0, const float* __restrict__ A1, int lda,
    const int* __restrict__ rowIdx,
    const u16* __restrict__ Bh0, const u16* __restrict__ Bl0,
    const u16* __restrict__ Bh1, const u16* __restrict__ Bl1,
    const float* __restrict__ bias0, const float* __restrict__ bias1,
    float* __restrict__ C0, float* __restrict__ C1, int ldc,
    int coff0, int coff1,
    const int* __restrict__ starts, int K)
{
    __shared__ short Ah[128 * AST], Al[128 * AST];
    __shared__ short Bh[128 * AST], Bl[128 * AST];

    const int tid = threadIdx.x;
    const int z = blockIdx.z;
    const float* A = z ? A1 : A0;
    const u16* Bhi = z ? Bh1 : Bh0;
    const u16* Blo = z ? Bl1 : Bl0;
    const float* bias = z ? bias1 : bias0;
    float* C = z ? C1 : C0;
    const int coff = z ? coff1 : coff0;

    const long rb = (long)blockIdx.x * 128;
    const int n0 = blockIdx.y * 128;
    const int t = (rb >= starts[0]) + (rb >= starts[1]);
    const u16* bhp = Bhi + ((long)t * 256 + n0) * K;
    const u16* blp = Blo + ((long)t * 256 + n0) * K;
    const float* biasT = bias + (long)t * 256 + n0;

    // A loader: 4 iters, each 32 rows x 32 k; thread -> (row, 4-float chunk)
    const int ar = tid >> 3;            // 0..31
    const int ac = (tid & 7) * 4;       // 0..28
    long arow[4]; float amask[4];
#pragma unroll
    for (int it = 0; it < 4; ++it) {
        int r = 32 * it + ar;
        if (GATHER) {
            int i0 = rowIdx[rb + r];
            amask[it] = (i0 < 0) ? 0.f : 1.f;
            arow[it] = (i0 < 0) ? 0 : (long)i0 * lda;
        } else {
            amask[it] = 1.f;
            arow[it] = (rb + r) * (long)lda;
        }
    }
    // B loader: 2 iters, each 64 rows(n) x 32 k; thread -> (n, 8-short chunk)
    const int bn = tid >> 2;            // 0..63
    const int bc = (tid & 3) * 8;       // 0..24

    // wave tiling
    const int wave = tid >> 6;
    const int lane = tid & 63;
    const int wr = (wave >> 1) * 64;
    const int wc = (wave & 1) * 64;
    const int lm = lane & 15;
    const int quad = lane >> 4;

    floatx4 acc[4][4];
#pragma unroll
    for (int i = 0; i < 4; ++i)
#pragma unroll
        for (int j = 0; j < 4; ++j) acc[i][j] = (floatx4){0.f, 0.f, 0.f, 0.f};

    for (int k0 = 0; k0 < K; k0 += 32) {
        // global prefetch
        float4 av[4];
#pragma unroll
        for (int it = 0; it < 4; ++it)
            av[it] = *(const float4*)(A + arow[it] + k0 + ac);
        short8 bhv[2], blv[2];
#pragma unroll
        for (int it = 0; it < 2; ++it) {
            long off = (long)(64 * it + bn) * K + k0 + bc;
            bhv[it] = *(const short8*)(bhp + off);
            blv[it] = *(const short8*)(blp + off);
        }
        __syncthreads();
        // A: convert fp32 -> bf16 hi/lo, store
#pragma unroll
        for (int it = 0; it < 4; ++it) {
            float xs[4] = {av[it].x, av[it].y, av[it].z, av[it].w};
            short4v hv, lv;
#pragma unroll
            for (int e = 0; e < 4; ++e) {
                float x = GATHER ? xs[e] * amask[it] : xs[e];
                u16 hh = f2bf(x);
                hv[e] = (short)hh;
                lv[e] = (short)f2bf(x - bf2f(hh));
            }
            int r = 32 * it + ar;
            *(short4v*)&Ah[r * AST + ac] = hv;
            *(short4v*)&Al[r * AST + ac] = lv;
        }
        // B: store
#pragma unroll
        for (int it = 0; it < 2; ++it) {
            int n = 64 * it + bn;
            *(short8*)&Bh[n * AST + bc] = bhv[it];
            *(short8*)&Bl[n * AST + bc] = blv[it];
        }
        __syncthreads();
        // fragments + MFMA
        short8 fah[4], fal[4];
#pragma unroll
        for (int i = 0; i < 4; ++i) {
            int m = wr + 16 * i + lm;
            fah[i] = *(const short8*)&Ah[m * AST + quad * 8];
            fal[i] = *(const short8*)&Al[m * AST + quad * 8];
        }
#pragma unroll
        for (int j = 0; j < 4; ++j) {
            int n = wc + 16 * j + lm;
            short8 fbh = *(const short8*)&Bh[n * AST + quad * 8];
            short8 fbl = *(const short8*)&Bl[n * AST + quad * 8];
#pragma unroll
            for (int i = 0; i < 4; ++i) {
                acc[i][j] = __builtin_amdgcn_mfma_f32_16x16x32_bf16(fah[i], fbh, acc[i][j], 0, 0, 0);
                acc[i][j] = __builtin_amdgcn_mfma_f32_16x16x32_bf16(fal[i], fbh, acc[i][j], 0, 0, 0);
                acc[i][j] = __builtin_amdgcn_mfma_f32_16x16x32_bf16(fah[i], fbl, acc[i][j], 0, 0, 0);
            }
        }
    }
    // epilogue
#pragma unroll
    for (int j = 0; j < 4; ++j) {
        int col = wc + 16 * j + lm;
        float bj = biasT[col];
#pragma unroll
        for (int i = 0; i < 4; ++i) {
            long rbase = rb + wr + 16 * i + quad * 4;
#pragma unroll
            for (int r = 0; r < 4; ++r) {
                float vv = acc[i][j][r] + bj;
                if (RELU) vv = fmaxf(vv, 0.f);
                C[(rbase + r) * (long)ldc + coff + n0 + col] = vv;
            }
        }
    }
}

// ---------------------------------------------------------------------------
// k_prep: per pair — denom, v-pool, z-pool, assemble XF/XH (1536 each).
// XF = [vs, poolf, zs(512), poolzf(512)], XH = [vs, poolh, zs, poolzh]
// ---------------------------------------------------------------------------
__global__ __launch_bounds__(256) void k_prep(
    const int* __restrict__ pairIdx, const int* __restrict__ prb,
    const float* __restrict__ dm, const float* __restrict__ v,
    const float* __restrict__ obs,
    float* __restrict__ XF, float* __restrict__ XH)
{
    int pv = blockIdx.x, c = threadIdx.x;
    int p = pairIdx[pv];
    float* xf = XF + (long)pv * 1536;
    float* xh = XH + (long)pv * 1536;
    if (p < 0) {
        for (int s = 0; s < 6; ++s) { xf[s * 256 + c] = 0.f; xh[s * 256 + c] = 0.f; }
        return;
    }
    __shared__ float sw[22];
    if (c < 22) sw[c] = dm[p * 22 + c];
    __syncthreads();
    float denf = 0.f, denh = 0.f;
    for (int e = 1; e < 12; ++e)  denf += sw[e];
    for (int e = 12; e < 22; ++e) denh += sw[e];
    denf = 1.f / fmaxf(denf, 1.f);
    denh = 1.f / fmaxf(denh, 1.f);

    long base = prb[pv];
    float vs = v[base * 256 + c];
    xf[c] = vs; xh[c] = vs;
    float af = 0.f, ah = 0.f;
    for (int e = 1; e < 12; ++e)  af += sw[e] * v[(base + e) * 256 + c];
    for (int e = 12; e < 22; ++e) ah += sw[e] * v[(base + e) * 256 + c];
    xf[256 + c] = af * denf;
    xh[256 + c] = ah * denh;
    const float* ob = obs + (long)p * 22 * 512;
    float w0 = sw[0];
    float z0 = ob[c] * w0;
    float z1 = ob[256 + c] * w0;
    xf[512 + c] = z0; xh[512 + c] = z0;
    xf[768 + c] = z1; xh[768 + c] = z1;
#pragma unroll
    for (int half = 0; half < 2; ++half) {
        int c2 = c + half * 256;
        float zf = 0.f, zh = 0.f;
        for (int e = 1; e < 12; ++e)  zf += sw[e] * ob[(long)e * 512 + c2];
        for (int e = 12; e < 22; ++e) zh += sw[e] * ob[(long)e * 512 + c2];
        xf[1024 + c2] = zf * denf;
        xh[1024 + c2] = zh * denh;
    }
}

// ---------------------------------------------------------------------------
// Final: L2 layer fused + logits + argmax + log-softmax + value dot; scatter.
// ---------------------------------------------------------------------------
__global__ __launch_bounds__(128) void k_final(
    const float* __restrict__ g1, const float* __restrict__ vV,
    const float* __restrict__ L2, const float* __restrict__ bL2,
    const float* __restrict__ L3, const float* __restrict__ bL3,
    const float* __restrict__ V2, const float* __restrict__ bV2,
    const int* __restrict__ pairIdx, const int* __restrict__ ps,
    float* __restrict__ out)
{
    int pv = blockIdx.x;
    int p = pairIdx[pv];
    if (p < 0) return;
    int c = threadIdx.x;
    int t = (pv >= ps[1]) + (pv >= ps[2]);

    __shared__ float sg1[256], sg2[128], sval[2];
    const float* g1p = g1 + (long)pv * 256;
    sg1[c] = g1p[c];
    sg1[c + 128] = g1p[c + 128];

    const float* vv = vV + (long)pv * 256;
    const float* v2t = V2 + t * 256;
    float s = vv[c] * v2t[c] + vv[c + 128] * v2t[c + 128];
    for (int off = 32; off; off >>= 1) s += __shfl_down(s, off);
    if ((c & 63) == 0) sval[c >> 6] = s;
    __syncthreads();

    const float* l2 = L2 + (long)t * 256 * 128 + c;
    float a = bL2[t * 128 + c];
#pragma unroll 8
    for (int k = 0; k < 256; ++k) a = fmaf(sg1[k], l2[(long)k * 128], a);
    sg2[c] = fmaxf(a, 0.f);
    __syncthreads();

    if (c < 64) {
        float lg = -3.0e38f;
        if (c < 21) {
            const float* l3t = L3 + (long)t * 128 * 21 + c;
            float acc = bL3[t * 21 + c];
            for (int k = 0; k < 128; ++k) acc = fmaf(sg2[k], l3t[k * 21], acc);
            lg = acc;
        }
        float mv = lg; int mi = (c < 21) ? c : 9999;
        for (int off = 32; off; off >>= 1) {
            float ov = __shfl_down(mv, off);
            int oi = __shfl_down(mi, off);
            if (ov > mv || (ov == mv && oi < mi)) { mv = ov; mi = oi; }
        }
        mv = __shfl(mv, 0); mi = __shfl(mi, 0);
        float e = (c < 21) ? expf(lg - mv) : 0.f;
        for (int off = 32; off; off >>= 1) e += __shfl_down(e, off);
        if (c == 0) {
            out[p] = (float)mi;
            out[NP_ + p] = sval[0] + sval[1] + bV2[t];
            out[2 * NP_ + p] = -logf(e);
        }
    }
}

// ---------------------------------------------------------------------------
extern "C" void kernel_launch(void* const* d_in, const int* in_sizes, int n_in,
                              void* d_out, int out_size, void* d_ws, size_t ws_size,
                              hipStream_t stream)
{
    const float* obs = (const float*)d_in[0];
    const int* hete = (const int*)d_in[1];
    const void* dead = d_in[2];
    const float* W1 = (const float*)d_in[3];  const float* b1 = (const float*)d_in[4];
    const float* W2 = (const float*)d_in[5];  const float* b2 = (const float*)d_in[6];
    const float* WCf = (const float*)d_in[7]; const float* bCf = (const float*)d_in[8];
    const float* WMf = (const float*)d_in[9]; const float* bMf = (const float*)d_in[10];
    const float* WCh = (const float*)d_in[11]; const float* bCh = (const float*)d_in[12];
    const float* WMh = (const float*)d_in[13]; const float* bMh = (const float*)d_in[14];
    const float* L1 = (const float*)d_in[15]; const float* bL1 = (const float*)d_in[16];
    const float* L2 = (const float*)d_in[17]; const float* bL2 = (const float*)d_in[18];
    const float* L3 = (const float*)d_in[19]; const float* bL3 = (const float*)d_in[20];
    const float* V1 = (const float*)d_in[21]; const float* bV1 = (const float*)d_in[22];
    const float* V2 = (const float*)d_in[23]; const float* bV2 = (const float*)d_in[24];
    float* out = (float*)d_out;

    // ---- workspace carve-up ----
    int* wsI = (int*)d_ws;
    int* pairIdx = wsI + 16;
    int* prb = pairIdx + PV_;
    int* rowObs = prb + PV_;
    long fbase = ((16L + PV_ + PV_ + RV_) + 63) & ~63L;
    float* wsF = (float*)d_ws;
    float* dm = wsF + fbase;
    float* cur = dm + NDEAD_;
    // bf16-split transposed weights (hi/lo per matrix), shorts = 3*256*K
    auto allocUS = [&](long K) { u16* p = (u16*)cur; cur += (3L * 256 * K) / 2; return p; };
    u16* W1h = allocUS(512);  u16* W1l = allocUS(512);
    u16* W2h = allocUS(256);  u16* W2l = allocUS(256);
    u16* WCfh = allocUS(512); u16* WCfl = allocUS(512);
    u16* WChh = allocUS(512); u16* WChl = allocUS(512);
    u16* WMfh = allocUS(1536); u16* WMfl = allocUS(1536);
    u16* WMhh = allocUS(1536); u16* WMhl = allocUS(1536);
    u16* L1h = allocUS(512);  u16* L1l = allocUS(512);
    u16* V1h = allocUS(512);  u16* V1l = allocUS(512);
    float* regA = cur;                               // RV_*256 floats
    float* regB = regA + (long)RV_ * 256;            // RV_*256 floats
    float* h1 = regA;                                // then XF/XH overlay
    float* XF = regA;
    float* XH = XF + (long)PV_ * 1536;
    float* v = regB;                                 // then head overlay
    float* vC = regB;
    float* vM = vC + (long)PV_ * 512;
    float* g1 = vM + (long)PV_ * 512;
    float* vV = g1 + (long)PV_ * 256;

    // ---- bookkeeping ----
    k_bucket<<<1, 256, 0, stream>>>((const unsigned*)dead, hete, wsI);
    k_deadmask<<<264, 256, 0, stream>>>(dead, wsI, dm);
    k_rowobs<<<266, 256, 0, stream>>>(wsI + 1, wsI + 4, wsI + 8, pairIdx, dm, rowObs);

    // ---- weight conversion (transpose + bf16 hi/lo split) ----
    k_wconv<<<3 * 512 / 8, 256, 0, stream>>>(W1, W1h, W1l, 512);
    k_wconv<<<3 * 256 / 8, 256, 0, stream>>>(W2, W2h, W2l, 256);
    k_wconv<<<3 * 512 / 8, 256, 0, stream>>>(WCf, WCfh, WCfl, 512);
    k_wconv<<<3 * 512 / 8, 256, 0, stream>>>(WCh, WChh, WChl, 512);
    k_wconv<<<3 * 1536 / 8, 256, 0, stream>>>(WMf, WMfh, WMfl, 1536);
    k_wconv<<<3 * 1536 / 8, 256, 0, stream>>>(WMh, WMhh, WMhl, 1536);
    k_wconv<<<3 * 512 / 8, 256, 0, stream>>>(L1, L1h, L1l, 512);
    k_wconv<<<3 * 512 / 8, 256, 0, stream>>>(V1, V1h, V1l, 512);

    // ---- phase 1 (entity rows, bucketed by type) ----
    k_mgemm<true, true><<<dim3(RV_ / 128, 2, 1), 256, 0, stream>>>(
        obs, obs, 512, rowObs, W1h, W1l, W1h, W1l, b1, b1,
        h1, h1, 256, 0, 0, wsI + 9, 512);
    k_mgemm<false, false><<<dim3(RV_ / 128, 2, 1), 256, 0, stream>>>(
        h1, h1, 256, nullptr, W2h, W2l, W2h, W2l, b2, b2,
        v, v, 256, 0, 0, wsI + 9, 256);

    // ---- pair prep ----
    k_prep<<<PV_, 256, 0, stream>>>(pairIdx, prb, dm, v, obs, XF, XH);

    // ---- heads (z-batched pairs) ----
    // H1: vC = [relu(XF@WCf) | relu(XH@WCh)]   K=512
    k_mgemm<false, true><<<dim3(PV_ / 128, 2, 2), 256, 0, stream>>>(
        XF, XH, 1536, nullptr, WCfh, WCfl, WChh, WChl, bCf, bCh,
        vC, vC, 512, 0, 256, wsI + 5, 512);
    // H2: vM = [relu(XF@WMf) | relu(XH@WMh)]   K=1536
    k_mgemm<false, true><<<dim3(PV_ / 128, 2, 2), 256, 0, stream>>>(
        XF, XH, 1536, nullptr, WMfh, WMfl, WMhh, WMhl, bMf, bMh,
        vM, vM, 512, 0, 256, wsI + 5, 1536);
    // H3: g1 = relu(vC@L1); vV = relu(vM@V1)   K=512
    k_mgemm<false, true><<<dim3(PV_ / 128, 2, 2), 256, 0, stream>>>(
        vC, vM, 512, nullptr, L1h, L1l, V1h, V1l, bL1, bV1,
        g1, vV, 256, 0, 0, wsI + 5, 512);

    k_final<<<PV_, 128, 0, stream>>>(g1, vV, L2, bL2, L3, bL3, V2, bV2,
                                     pairIdx, wsI + 4, out);
    (void)in_sizes; (void)n_in; (void)out_size; (void)ws_size;
}